// Round 1
// 160.652 us; speedup vs baseline: 1.0022x; 1.0022x over previous
//
#include <hip/hip_runtime.h>
#include <math.h>

constexpr int Bc = 2, Lc = 256, DMc = 256, Hc = 8, DHc = 32;
constexpr float LOG2E = 1.4426950408889634f;
constexpr float RSQRT_DH = 0.17677669529663687f; // 1/sqrt(32)
#define EXP2 __builtin_amdgcn_exp2f

// Gaussian-mixture tabulation parameters.
// G_{h,tau}(x) = sum_{d,k} w*exp(-(x-mu)^2/(2 sg^2)) is a 1-D function on x in [0,1).
// Piecewise-quadratic table, 512 intervals (samples on 1/1024 grid).
// Gaussians with sg < SIG0 are excluded from the table (would alias) and kept in an
// exact per-(h,tau) compacted list. Borderline interp error ~3e-7 per Gaussian.
constexpr int   NTAB = 512;
constexpr float SIG0 = 0.08f;

// ===========================================================================
// k_tab: build per-(h,tau) tables + narrow lists for g_rel params.
// grid 128 = 32 (h,tau) x 4 chunks; each chunk covers 128 intervals (257 samples).
// ===========================================================================
__device__ __forceinline__ float mixsum(const float4* __restrict__ prm, float x) {
    float acc = 0.f;
    #pragma unroll 8
    for (int q = 0; q < 128; ++q) {
        float4 p = prm[q];          // (mu, n, w_masked, 0), wave-uniform ds_read
        float d0 = x - p.x;
        acc = fmaf(p.z, EXP2(d0 * d0 * p.y), acc);
    }
    return acc;
}

__global__ void __launch_bounds__(256) k_tab(
    const float* __restrict__ mu, const float* __restrict__ sg, const float* __restrict__ w,
    float4* __restrict__ TAB, float4* __restrict__ NLIST, int* __restrict__ NCNT)
{
    __shared__ float4 prm[128];
    __shared__ float fs[260];
    int bx = blockIdx.x;
    int hm = bx >> 2, chunk = bx & 3;      // hm = h*4+tau
    int h = hm >> 2, tau = hm & 3;
    int tid = threadIdx.x;

    if (tid < 128) {
        int d = tid >> 2, k = tid & 3;
        int off = h * 512 + d * 16 + tau * 4 + k;
        float s = sg[off];
        float n = -(0.5f * LOG2E) / (s * s);
        prm[tid] = make_float4(mu[off], n, (s < SIG0) ? 0.0f : w[off], 0.0f);
    }
    if (chunk == 0 && tid == 0) {
        // compacted exact list for narrow Gaussians (stable (x-mu)^2 form)
        int cnt = 0;
        for (int d = 0; d < 32; ++d)
            for (int k = 0; k < 4; ++k) {
                int off = h * 512 + d * 16 + tau * 4 + k;
                float s = sg[off];
                if (s < SIG0) {
                    float n = -(0.5f * LOG2E) / (s * s);
                    NLIST[hm * 128 + cnt] = make_float4(mu[off], n, w[off], 0.0f);
                    ++cnt;
                }
            }
        NCNT[hm] = cnt;
    }
    __syncthreads();

    // samples at x = (chunk*256 + s)/1024, s = 0..256
    fs[tid] = mixsum(prm, (float)(chunk * 256 + tid) * (1.0f / 1024.0f));
    if (tid == 0)
        fs[256] = mixsum(prm, (float)(chunk * 256 + 256) * (1.0f / 1024.0f));
    __syncthreads();

    if (tid < 128) {
        float f0 = fs[tid * 2], fm = fs[tid * 2 + 1], f1 = fs[tid * 2 + 2];
        // quadratic in u = x*NTAB - i  (u in [0,1)): G ~ c0 + c1*u + c2*u^2
        float c2 = 2.0f * (f0 + f1 - 2.0f * fm);
        float c1 = f1 - f0 - c2;
        TAB[hm * NTAB + chunk * 128 + tid] = make_float4(f0, c1, c2, 0.0f);
    }
}

// ===========================================================================
// k_gauss: g_rel via table lookup + exact narrow residual.
// grid 272 = 16 (b,h) x 17 chunks; each block: stage 4 tau-tables (32KB LDS),
// then 8 symmetric 16x16 tile-pairs (1 point/thread/pair).
// ===========================================================================
__global__ void __launch_bounds__(256) k_gauss(
    const float* __restrict__ t, const float4* __restrict__ TAB,
    const float4* __restrict__ NLIST, const int* __restrict__ NCNT,
    float* __restrict__ GR)
{
    __shared__ float4 tab[4 * NTAB];     // 32 KB
    __shared__ float lt[16 * 17];
    int bx = blockIdx.x;
    int bh = bx / 17, chunk = bx - bh * 17;
    int b = bh >> 3, h = bh & 7;
    int tid = threadIdx.x;

    const float4* src = TAB + h * 4 * NTAB;
    #pragma unroll
    for (int u = 0; u < (4 * NTAB) / 256; ++u)
        tab[tid + u * 256] = src[tid + u * 256];
    int cnt[4];
    #pragma unroll
    for (int tg = 0; tg < 4; ++tg) cnt[tg] = NCNT[h * 4 + tg];
    __syncthreads();

    float* gb = GR + (size_t)bh * (Lc * Lc);
    int di = tid >> 4, dj = tid & 15;

    for (int pi = 0; pi < 8; ++pi) {
        int p = chunk * 8 + pi;          // 0..135, block-uniform
        int ti = 0, pp = p;
        for (;; ++ti) { int c = 16 - ti; if (pp < c) break; pp -= c; }
        int tj = ti + pp;
        int i = ti * 16 + di, j = tj * 16 + dj;
        float4 t_i = *(const float4*)(t + (b * Lc + i) * 4);
        float4 t_j = *(const float4*)(t + (b * Lc + j) * 4);
        float tr[4] = {fabsf(t_i.x - t_j.x), fabsf(t_i.y - t_j.y),
                       fabsf(t_i.z - t_j.z), fabsf(t_i.w - t_j.w)};
        float g = 0.f;
        #pragma unroll
        for (int tg = 0; tg < 4; ++tg) {
            float x = tr[tg];
            float xs = x * (float)NTAB;
            int iu = (int)xs; iu = min(iu, NTAB - 1);
            float uu = xs - (float)iu;
            float4 c = tab[tg * NTAB + iu];                 // per-lane gather
            float val = fmaf(uu, fmaf(uu, c.z, c.y), c.x);  // table part
            int cn = cnt[tg];                               // wave-uniform trip count
            for (int nn = 0; nn < cn; ++nn) {
                float4 q = NLIST[(h * 4 + tg) * 128 + nn];  // uniform -> s_load
                float d0 = x - q.x;
                val = fmaf(q.z, EXP2(d0 * d0 * q.y), val);  // exact narrow part
            }
            g += val;
        }
        g *= (1.0f / 32.0f);
        gb[i * Lc + j] = g;
        if (ti != tj) {                  // block-uniform branch: syncs are safe
            __syncthreads();             // protect lt reuse across pairs
            lt[di * 17 + dj] = g;
            __syncthreads();
            gb[(tj * 16 + di) * Lc + (ti * 16 + dj)] = lt[dj * 17 + di];
        }
    }
}

// ===========================================================================
// role_gabs (exact, unchanged): only 64 blocks — not worth tabulating.
// ===========================================================================
__device__ __forceinline__ void role_gabs(int idx, const float* __restrict__ t,
                                          const float* __restrict__ mu, const float* __restrict__ sg,
                                          const float* __restrict__ w, float* __restrict__ gabs,
                                          float* smem) {
    int h = idx & 7, b = (idx >> 3) & 1, q = idx >> 4;   // q: i-quarter
    int tid = threadIdx.x;
    {
        float2 s2 = *(const float2*)(sg + h * 512 + tid * 2);
        float2 o;
        o.x = -(0.5f * LOG2E) / (s2.x * s2.x);
        o.y = -(0.5f * LOG2E) / (s2.y * s2.y);
        *(float2*)(smem + tid * 2) = o;
    }
    __syncthreads();
    int lane = tid & 63, tg = tid >> 6;
    int i = q * 64 + lane;
    float tv = t[(b * Lc + i) * 4 + tg];
    const float* muB = mu + h * 512 + tg * 4;
    const float* wB  = w  + h * 512 + tg * 4;
    const float* nsB = smem + tg * 4;
    float acc = 0.f;
    #pragma unroll 4
    for (int d = 0; d < 32; ++d) {
        float4 m4 = *(const float4*)(muB + d * 16);
        float4 w4 = *(const float4*)(wB  + d * 16);
        float4 n4 = *(const float4*)(nsB + d * 16);
        float d0 = tv - m4.x; acc = fmaf(w4.x, EXP2(d0 * d0 * n4.x), acc);
        float d1 = tv - m4.y; acc = fmaf(w4.y, EXP2(d1 * d1 * n4.y), acc);
        float d2 = tv - m4.z; acc = fmaf(w4.z, EXP2(d2 * d2 * n4.z), acc);
        float d3 = tv - m4.w; acc = fmaf(w4.w, EXP2(d3 * d3 * n4.w), acc);
    }
    float* red = smem + 512;   // 4 x 64
    red[tg * 64 + lane] = acc;
    __syncthreads();
    if (tid < 64)
        gabs[(b * Hc + h) * Lc + q * 64 + lane] =
            (red[lane] + red[64 + lane] + red[128 + lane] + red[192 + lane]) * (1.0f / 32.0f);
}

template<int R, int PER>
__device__ __forceinline__ void stage_tile(const float* __restrict__ src, int ld,
                                           int row0, int k0, float* __restrict__ dst, int tid) {
    int row = tid / (16 / PER);
    int cb = (tid % (16 / PER)) * PER;
    const float* g = src + (size_t)(row0 + row) * ld + k0 + cb;
    float v[PER];
    #pragma unroll
    for (int u = 0; u < PER; ++u) v[u] = g[u];
    #pragma unroll
    for (int u = 0; u < PER; ++u) dst[(cb + u) * (R + 1) + row] = v[u];
}

__device__ __forceinline__ void gemm32(const float* __restrict__ A, const float* __restrict__ W,
                                       float* __restrict__ C, const float* __restrict__ bias,
                                       float sc, int m0, int n0, float* smem) {
    // C[m0:+32, n0:+32] = sc * A[.,K=256] @ W^T (+bias); LDS [k][m] pitch 33.
    float* As = smem;
    float* Ws = smem + 16 * 33;
    int tid = threadIdx.x;
    int tx = tid & 15, ty = tid >> 4;
    float acc[2][2] = {};
    for (int k0 = 0; k0 < 256; k0 += 16) {
        stage_tile<32, 2>(A, 256, m0, k0, As, tid);
        stage_tile<32, 2>(W, 256, n0, k0, Ws, tid);
        __syncthreads();
        #pragma unroll
        for (int k = 0; k < 16; ++k) {
            float a0 = As[k * 33 + ty * 2], a1 = As[k * 33 + ty * 2 + 1];
            float w0 = Ws[k * 33 + tx * 2], w1 = Ws[k * 33 + tx * 2 + 1];
            acc[0][0] = fmaf(a0, w0, acc[0][0]);
            acc[0][1] = fmaf(a0, w1, acc[0][1]);
            acc[1][0] = fmaf(a1, w0, acc[1][0]);
            acc[1][1] = fmaf(a1, w1, acc[1][1]);
        }
        __syncthreads();
    }
    #pragma unroll
    for (int u = 0; u < 2; ++u) {
        int m = m0 + ty * 2 + u;
        #pragma unroll
        for (int v = 0; v < 2; ++v) {
            float o = acc[u][v] * sc;
            if (bias) o += bias[n0 + tx * 2 + v];
            C[(size_t)m * DMc + n0 + tx * 2 + v] = o;
        }
    }
}

// ===========================================================================
// k_qkv: gabs (64 blocks) + QKV gemms (384 blocks). Split from old kA so the
// gemm role keeps its small-LDS occupancy (grel's table LDS lives in k_gauss).
// ===========================================================================
__global__ void __launch_bounds__(256) k_qkv(
    const float* __restrict__ x, const float* __restrict__ t,
    const float* __restrict__ WQ, const float* __restrict__ WK, const float* __restrict__ WV,
    const float* __restrict__ mu_a, const float* __restrict__ sg_a, const float* __restrict__ w_a,
    float* __restrict__ Qb, float* __restrict__ Kb, float* __restrict__ Vb,
    float* __restrict__ GA)
{
    __shared__ float smem[1056];
    int bx = blockIdx.x;
    if (bx < 64) {
        role_gabs(bx, t, mu_a, sg_a, w_a, GA, smem);
    } else {
        int idx = bx - 64;            // 0..383
        int z = idx >> 7;             // 0:Q 1:K 2:V
        int r = idx & 127;
        int m0 = (r >> 3) * 32, n0 = (r & 7) * 32;
        const float* W = (z == 0) ? WQ : (z == 1) ? WK : WV;
        float* C = (z == 0) ? Qb : (z == 1) ? Kb : Vb;
        gemm32(x, W, C, nullptr, (z == 0) ? RSQRT_DH : 1.0f, m0, n0, smem);
    }
}

// ===========================================================================
// kB: S = Q@K^T (Q pre-scaled), P = X@X^T; 64x64 tiles, K=32. Fused
// modulation logit = S*(P*(2*alpha*g_abs + beta*g_rel)+gamma), in-place on GR.
// grid (4,4,16). [unchanged — proven]
// ===========================================================================
__global__ void __launch_bounds__(256) k_sp(
    const float* __restrict__ Q, const float* __restrict__ K, const float* __restrict__ x,
    const float* __restrict__ gabs,
    const float* __restrict__ alpha, const float* __restrict__ beta, const float* __restrict__ gamma,
    float* __restrict__ G)
{
    constexpr int PITCH = 68;
    int it = blockIdx.x, jt = blockIdx.y, bh = blockIdx.z;
    int b = bh >> 3, h = bh & 7;
    int i0 = it * 64, j0 = jt * 64;
    int tid = threadIdx.x;
    __shared__ float sm[4 * 32 * PITCH];
    float* sQ  = sm;
    float* sK  = sm + 32 * PITCH;
    float* sXi = sm + 64 * PITCH;
    float* sXj = sm + 96 * PITCH;

    int r0 = tid >> 3;
    int c4 = (tid & 7) * 4;
    #pragma unroll
    for (int uu = 0; uu < 2; ++uu) {
        int r = r0 + uu * 32;
        float4 qv = *(const float4*)(Q + ((size_t)(b * Lc + i0 + r) * DMc + h * DHc + c4));
        float4 kv = *(const float4*)(K + ((size_t)(b * Lc + j0 + r) * DMc + h * DHc + c4));
        float4 xi = *(const float4*)(x + ((size_t)(b * Lc + i0 + r) * DMc + h * DHc + c4));
        float4 xj = *(const float4*)(x + ((size_t)(b * Lc + j0 + r) * DMc + h * DHc + c4));
        const float* q_ = (const float*)&qv; const float* k_ = (const float*)&kv;
        const float* a_ = (const float*)&xi; const float* c_ = (const float*)&xj;
        #pragma unroll
        for (int u = 0; u < 4; ++u) {
            sQ [(c4 + u) * PITCH + r] = q_[u];
            sK [(c4 + u) * PITCH + r] = k_[u];
            sXi[(c4 + u) * PITCH + r] = a_[u];
            sXj[(c4 + u) * PITCH + r] = c_[u];
        }
    }
    __syncthreads();

    int tx = tid & 15, ty = tid >> 4;
    int i4 = ty * 4, j4 = tx * 4;
    float accS[4][4] = {}, accP[4][4] = {};
    #pragma unroll 4
    for (int k = 0; k < 32; ++k) {
        float4 qa = *(const float4*)(sQ  + k * PITCH + i4);
        float4 kb = *(const float4*)(sK  + k * PITCH + j4);
        float4 xa = *(const float4*)(sXi + k * PITCH + i4);
        float4 xb = *(const float4*)(sXj + k * PITCH + j4);
        const float* qa_ = (const float*)&qa; const float* kb_ = (const float*)&kb;
        const float* xa_ = (const float*)&xa; const float* xb_ = (const float*)&xb;
        #pragma unroll
        for (int u = 0; u < 4; ++u)
            #pragma unroll
            for (int v = 0; v < 4; ++v) {
                accS[u][v] = fmaf(qa_[u], kb_[v], accS[u][v]);
                accP[u][v] = fmaf(xa_[u], xb_[v], accP[u][v]);
            }
    }

    float la = alpha[h], lb = beta[h], lg = gamma[h];
    float* gb = G + (size_t)bh * (Lc * Lc);
    #pragma unroll
    for (int u = 0; u < 4; ++u) {
        int i = i0 + i4 + u;
        float gi2 = 2.0f * la * gabs[bh * Lc + i];
        float* addr = gb + (size_t)i * Lc + j0 + j4;
        float4 gr = *(const float4*)addr;
        float4 o;
        o.x = accS[u][0] * fmaf(accP[u][0], fmaf(lb, gr.x, gi2), lg);
        o.y = accS[u][1] * fmaf(accP[u][1], fmaf(lb, gr.y, gi2), lg);
        o.z = accS[u][2] * fmaf(accP[u][2], fmaf(lb, gr.z, gi2), lg);
        o.w = accS[u][3] * fmaf(accP[u][3], fmaf(lb, gr.w, gi2), lg);
        *(float4*)addr = o;
    }
}

// ===========================================================================
// kC: softmax fused into PV. grid (16 i-tiles, 16 bh), block 256. [unchanged]
// ===========================================================================
__global__ void __launch_bounds__(256) k_pvsm(const float* __restrict__ P,
                                              const float* __restrict__ V,
                                              float* __restrict__ AO) {
    int it = blockIdx.x, bh = blockIdx.y;
    int b = bh >> 3, h = bh & 7;
    int i0 = it * 16;
    int tid = threadIdx.x;
    __shared__ float sP[16 * 260];
    __shared__ float sV[256 * 34];
    int i = tid >> 4, l = tid & 15;

    const float* row = P + (size_t)bh * (Lc * Lc) + (size_t)(i0 + i) * Lc + l * 16;
    float4 p0 = *(const float4*)(row);
    float4 p1 = *(const float4*)(row + 4);
    float4 p2 = *(const float4*)(row + 8);
    float4 p3 = *(const float4*)(row + 12);
    float m = fmaxf(fmaxf(fmaxf(p0.x, p0.y), fmaxf(p0.z, p0.w)),
                    fmaxf(fmaxf(p1.x, p1.y), fmaxf(p1.z, p1.w)));
    m = fmaxf(m, fmaxf(fmaxf(fmaxf(p2.x, p2.y), fmaxf(p2.z, p2.w)),
                       fmaxf(fmaxf(p3.x, p3.y), fmaxf(p3.z, p3.w))));
    #pragma unroll
    for (int s = 1; s < 16; s <<= 1) m = fmaxf(m, __shfl_xor(m, s, 64));
    float4 e0, e1, e2, e3;
    e0.x = EXP2((p0.x - m) * LOG2E); e0.y = EXP2((p0.y - m) * LOG2E);
    e0.z = EXP2((p0.z - m) * LOG2E); e0.w = EXP2((p0.w - m) * LOG2E);
    e1.x = EXP2((p1.x - m) * LOG2E); e1.y = EXP2((p1.y - m) * LOG2E);
    e1.z = EXP2((p1.z - m) * LOG2E); e1.w = EXP2((p1.w - m) * LOG2E);
    e2.x = EXP2((p2.x - m) * LOG2E); e2.y = EXP2((p2.y - m) * LOG2E);
    e2.z = EXP2((p2.z - m) * LOG2E); e2.w = EXP2((p2.w - m) * LOG2E);
    e3.x = EXP2((p3.x - m) * LOG2E); e3.y = EXP2((p3.y - m) * LOG2E);
    e3.z = EXP2((p3.z - m) * LOG2E); e3.w = EXP2((p3.w - m) * LOG2E);
    float sum = ((e0.x + e0.y) + (e0.z + e0.w)) + ((e1.x + e1.y) + (e1.z + e1.w)) +
                ((e2.x + e2.y) + (e2.z + e2.w)) + ((e3.x + e3.y) + (e3.z + e3.w));
    #pragma unroll
    for (int s = 1; s < 16; s <<= 1) sum += __shfl_xor(sum, s, 64);
    float rs = 1.0f / sum;
    *(float4*)(sP + i * 260 + l * 16)      = e0;
    *(float4*)(sP + i * 260 + l * 16 + 4)  = e1;
    *(float4*)(sP + i * 260 + l * 16 + 8)  = e2;
    *(float4*)(sP + i * 260 + l * 16 + 12) = e3;

    int jj = tid >> 3, c4 = (tid & 7) * 4;
    #pragma unroll
    for (int u = 0; u < 8; ++u) {
        int j = jj + u * 32;
        *(float4*)(sV + j * 34 + c4) =
            *(const float4*)(V + ((size_t)(b * Lc + j) * DMc + h * DHc + c4));
    }
    __syncthreads();

    int d2 = l * 2;
    float o0 = 0.f, o1 = 0.f;
    #pragma unroll 2
    for (int j4 = 0; j4 < 256; j4 += 4) {
        float4 p4 = *(const float4*)(sP + i * 260 + j4);
        float2 v0 = *(const float2*)(sV + (j4 + 0) * 34 + d2);
        float2 v1 = *(const float2*)(sV + (j4 + 1) * 34 + d2);
        float2 v2 = *(const float2*)(sV + (j4 + 2) * 34 + d2);
        float2 v3 = *(const float2*)(sV + (j4 + 3) * 34 + d2);
        o0 += p4.x * v0.x + p4.y * v1.x + p4.z * v2.x + p4.w * v3.x;
        o1 += p4.x * v0.y + p4.y * v1.y + p4.z * v2.y + p4.w * v3.y;
    }
    *(float2*)(AO + ((size_t)(b * Lc + i0 + i) * DMc + h * DHc + d2)) =
        make_float2(o0 * rs, o1 * rs);
}

// ===========================================================================
// kD: out = AO @ WO^T + bO.  grid (16,8), 32x32 tiles. [unchanged]
// ===========================================================================
__global__ void __launch_bounds__(256) k_out(const float* __restrict__ A,
                                             const float* __restrict__ W,
                                             const float* __restrict__ bias,
                                             float* __restrict__ C) {
    __shared__ float smem[2 * 16 * 33];
    gemm32(A, W, C, bias, 1.0f, blockIdx.x * 32, blockIdx.y * 32, smem);
}

// ===========================================================================
extern "C" void kernel_launch(void* const* d_in, const int* in_sizes, int n_in,
                              void* d_out, int out_size, void* d_ws, size_t ws_size,
                              hipStream_t stream) {
    (void)in_sizes; (void)n_in; (void)out_size; (void)ws_size;
    const float* x      = (const float*)d_in[0];
    const float* t      = (const float*)d_in[1];
    const float* WQ     = (const float*)d_in[2];
    const float* WK     = (const float*)d_in[3];
    const float* WV     = (const float*)d_in[4];
    const float* WO     = (const float*)d_in[5];
    const float* bO     = (const float*)d_in[6];
    const float* mu_abs = (const float*)d_in[7];
    const float* sg_abs = (const float*)d_in[8];
    const float* w_abs  = (const float*)d_in[9];
    const float* mu_rel = (const float*)d_in[10];
    const float* sg_rel = (const float*)d_in[11];
    const float* w_rel  = (const float*)d_in[12];
    const float* alpha  = (const float*)d_in[13];
    const float* beta   = (const float*)d_in[14];
    const float* gamma  = (const float*)d_in[15];
    float* out = (float*)d_out;
    float* ws = (float*)d_ws;

    float* Qb = ws;                // 131072 floats
    float* Kb = ws + 131072;
    float* Vb = ws + 262144;
    float* AO = ws + 393216;
    float* GA = ws + 524288;       // 4096
    float* GR = ws + 528384;       // 1048576 (g_rel -> logits)
    float4* TAB   = (float4*)(ws + 1576960);   // 32 x 512 x float4 = 65536 floats
    float4* NLIST = (float4*)(ws + 1642496);   // 32 x 128 x float4 = 16384 floats
    int*    NCNT  = (int*)   (ws + 1658880);   // 32 ints

    k_tab<<<dim3(128), dim3(256), 0, stream>>>(mu_rel, sg_rel, w_rel, TAB, NLIST, NCNT);
    k_qkv<<<dim3(448), dim3(256), 0, stream>>>(x, t, WQ, WK, WV,
                                               mu_abs, sg_abs, w_abs, Qb, Kb, Vb, GA);
    k_gauss<<<dim3(272), dim3(256), 0, stream>>>(t, TAB, NLIST, NCNT, GR);
    k_sp<<<dim3(4, 4, 16), dim3(256), 0, stream>>>(Qb, Kb, x, GA, alpha, beta, gamma, GR);
    k_pvsm<<<dim3(16, 16), dim3(256), 0, stream>>>(GR, Vb, AO);
    k_out<<<dim3(16, 8), dim3(256), 0, stream>>>(AO, WO, bO, out);
}

// Round 2
// 147.296 us; speedup vs baseline: 1.0931x; 1.0907x over previous
//
#include <hip/hip_runtime.h>
#include <math.h>

constexpr int Bc = 2, Lc = 256, DMc = 256, Hc = 8, DHc = 32;
constexpr float LOG2E = 1.4426950408889634f;
constexpr float RSQRT_DH = 0.17677669529663687f; // 1/sqrt(32)
#define EXP2 __builtin_amdgcn_exp2f

// Gaussian-mixture tabulation parameters (see R0 notes).
constexpr int   NTAB = 512;
constexpr float SIG0 = 0.08f;

// ===========================================================================
// role_tab: build per-(h,tau) piecewise-quadratic tables + narrow lists.
// 128 blocks = 32 (h,tau) x 4 chunks; each chunk covers 128 intervals.
// Narrow-list build is PARALLEL (LDS atomic compaction) — the old serial
// tid==0 version was a single-lane chain of ~128 HBM-latency loads (~50us)
// that stalled the whole stream.
// ===========================================================================
__device__ __forceinline__ float mixsum(const float4* __restrict__ prm, float x) {
    float acc = 0.f;
    #pragma unroll 8
    for (int q = 0; q < 128; ++q) {
        float4 p = prm[q];          // (mu, n, w_masked, 0), wave-uniform ds_read
        float d0 = x - p.x;
        acc = fmaf(p.z, EXP2(d0 * d0 * p.y), acc);
    }
    return acc;
}

__device__ __forceinline__ void role_tab(int bx,
    const float* __restrict__ mu, const float* __restrict__ sg, const float* __restrict__ w,
    float4* __restrict__ TAB, float4* __restrict__ NLIST, int* __restrict__ NCNT,
    float* smem)
{
    float4* prm = (float4*)smem;      // 128 float4 = 512 floats
    float*  fs  = smem + 512;         // 260 floats
    int*    lcnt = (int*)(smem + 772);
    int hm = bx >> 2, chunk = bx & 3;      // hm = h*4+tau
    int h = hm >> 2, tau = hm & 3;
    int tid = threadIdx.x;

    if (tid == 0) *lcnt = 0;
    __syncthreads();
    if (tid < 128) {
        int d = tid >> 2, k = tid & 3;
        int off = h * 512 + d * 16 + tau * 4 + k;
        float s  = sg[off];
        float mv = mu[off], wv = w[off];
        float n = -(0.5f * LOG2E) / (s * s);
        bool narrow = (s < SIG0);
        prm[tid] = make_float4(mv, n, narrow ? 0.0f : wv, 0.0f);
        if (chunk == 0 && narrow) {
            int slot = atomicAdd(lcnt, 1);      // order irrelevant: summed later
            NLIST[hm * 128 + slot] = make_float4(mv, n, wv, 0.0f);
        }
    }
    __syncthreads();
    if (chunk == 0 && tid == 0) NCNT[hm] = *lcnt;

    // samples at x = (chunk*256 + s)/1024, s = 0..256
    fs[tid] = mixsum(prm, (float)(chunk * 256 + tid) * (1.0f / 1024.0f));
    if (tid == 0)
        fs[256] = mixsum(prm, (float)(chunk * 256 + 256) * (1.0f / 1024.0f));
    __syncthreads();

    if (tid < 128) {
        float f0 = fs[tid * 2], fm = fs[tid * 2 + 1], f1 = fs[tid * 2 + 2];
        // quadratic in u = x*NTAB - i (u in [0,1)): G ~ c0 + c1*u + c2*u^2
        float c2 = 2.0f * (f0 + f1 - 2.0f * fm);
        float c1 = f1 - f0 - c2;
        TAB[hm * NTAB + chunk * 128 + tid] = make_float4(f0, c1, c2, 0.0f);
    }
}

// ===========================================================================
// k_gauss: g_rel via table lookup + exact narrow residual. [unchanged]
// grid 272 = 16 (b,h) x 17 chunks.
// ===========================================================================
__global__ void __launch_bounds__(256) k_gauss(
    const float* __restrict__ t, const float4* __restrict__ TAB,
    const float4* __restrict__ NLIST, const int* __restrict__ NCNT,
    float* __restrict__ GR)
{
    __shared__ float4 tab[4 * NTAB];     // 32 KB
    __shared__ float lt[16 * 17];
    int bx = blockIdx.x;
    int bh = bx / 17, chunk = bx - bh * 17;
    int b = bh >> 3, h = bh & 7;
    int tid = threadIdx.x;

    const float4* src = TAB + h * 4 * NTAB;
    #pragma unroll
    for (int u = 0; u < (4 * NTAB) / 256; ++u)
        tab[tid + u * 256] = src[tid + u * 256];
    int cnt[4];
    #pragma unroll
    for (int tg = 0; tg < 4; ++tg) cnt[tg] = NCNT[h * 4 + tg];
    __syncthreads();

    float* gb = GR + (size_t)bh * (Lc * Lc);
    int di = tid >> 4, dj = tid & 15;

    for (int pi = 0; pi < 8; ++pi) {
        int p = chunk * 8 + pi;          // 0..135, block-uniform
        int ti = 0, pp = p;
        for (;; ++ti) { int c = 16 - ti; if (pp < c) break; pp -= c; }
        int tj = ti + pp;
        int i = ti * 16 + di, j = tj * 16 + dj;
        float4 t_i = *(const float4*)(t + (b * Lc + i) * 4);
        float4 t_j = *(const float4*)(t + (b * Lc + j) * 4);
        float tr[4] = {fabsf(t_i.x - t_j.x), fabsf(t_i.y - t_j.y),
                       fabsf(t_i.z - t_j.z), fabsf(t_i.w - t_j.w)};
        float g = 0.f;
        #pragma unroll
        for (int tg = 0; tg < 4; ++tg) {
            float x = tr[tg];
            float xs = x * (float)NTAB;
            int iu = (int)xs; iu = min(iu, NTAB - 1);
            float uu = xs - (float)iu;
            float4 c = tab[tg * NTAB + iu];                 // per-lane gather
            float val = fmaf(uu, fmaf(uu, c.z, c.y), c.x);  // table part
            int cn = cnt[tg];                               // wave-uniform trip count
            for (int nn = 0; nn < cn; ++nn) {
                float4 q = NLIST[(h * 4 + tg) * 128 + nn];  // uniform -> s_load
                float d0 = x - q.x;
                val = fmaf(q.z, EXP2(d0 * d0 * q.y), val);  // exact narrow part
            }
            g += val;
        }
        g *= (1.0f / 32.0f);
        gb[i * Lc + j] = g;
        if (ti != tj) {                  // block-uniform branch: syncs are safe
            __syncthreads();             // protect lt reuse across pairs
            lt[di * 17 + dj] = g;
            __syncthreads();
            gb[(tj * 16 + di) * Lc + (ti * 16 + dj)] = lt[dj * 17 + di];
        }
    }
}

// ===========================================================================
// role_gabs (exact): only 64 blocks — not worth tabulating. [unchanged]
// ===========================================================================
__device__ __forceinline__ void role_gabs(int idx, const float* __restrict__ t,
                                          const float* __restrict__ mu, const float* __restrict__ sg,
                                          const float* __restrict__ w, float* __restrict__ gabs,
                                          float* smem) {
    int h = idx & 7, b = (idx >> 3) & 1, q = idx >> 4;   // q: i-quarter
    int tid = threadIdx.x;
    {
        float2 s2 = *(const float2*)(sg + h * 512 + tid * 2);
        float2 o;
        o.x = -(0.5f * LOG2E) / (s2.x * s2.x);
        o.y = -(0.5f * LOG2E) / (s2.y * s2.y);
        *(float2*)(smem + tid * 2) = o;
    }
    __syncthreads();
    int lane = tid & 63, tg = tid >> 6;
    int i = q * 64 + lane;
    float tv = t[(b * Lc + i) * 4 + tg];
    const float* muB = mu + h * 512 + tg * 4;
    const float* wB  = w  + h * 512 + tg * 4;
    const float* nsB = smem + tg * 4;
    float acc = 0.f;
    #pragma unroll 4
    for (int d = 0; d < 32; ++d) {
        float4 m4 = *(const float4*)(muB + d * 16);
        float4 w4 = *(const float4*)(wB  + d * 16);
        float4 n4 = *(const float4*)(nsB + d * 16);
        float d0 = tv - m4.x; acc = fmaf(w4.x, EXP2(d0 * d0 * n4.x), acc);
        float d1 = tv - m4.y; acc = fmaf(w4.y, EXP2(d1 * d1 * n4.y), acc);
        float d2 = tv - m4.z; acc = fmaf(w4.z, EXP2(d2 * d2 * n4.z), acc);
        float d3 = tv - m4.w; acc = fmaf(w4.w, EXP2(d3 * d3 * n4.w), acc);
    }
    float* red = smem + 512;   // 4 x 64
    red[tg * 64 + lane] = acc;
    __syncthreads();
    if (tid < 64)
        gabs[(b * Hc + h) * Lc + q * 64 + lane] =
            (red[lane] + red[64 + lane] + red[128 + lane] + red[192 + lane]) * (1.0f / 32.0f);
}

template<int R, int PER>
__device__ __forceinline__ void stage_tile(const float* __restrict__ src, int ld,
                                           int row0, int k0, float* __restrict__ dst, int tid) {
    int row = tid / (16 / PER);
    int cb = (tid % (16 / PER)) * PER;
    const float* g = src + (size_t)(row0 + row) * ld + k0 + cb;
    float v[PER];
    #pragma unroll
    for (int u = 0; u < PER; ++u) v[u] = g[u];
    #pragma unroll
    for (int u = 0; u < PER; ++u) dst[(cb + u) * (R + 1) + row] = v[u];
}

__device__ __forceinline__ void gemm32(const float* __restrict__ A, const float* __restrict__ W,
                                       float* __restrict__ C, const float* __restrict__ bias,
                                       float sc, int m0, int n0, float* smem) {
    // C[m0:+32, n0:+32] = sc * A[.,K=256] @ W^T (+bias); LDS [k][m] pitch 33.
    float* As = smem;
    float* Ws = smem + 16 * 33;
    int tid = threadIdx.x;
    int tx = tid & 15, ty = tid >> 4;
    float acc[2][2] = {};
    for (int k0 = 0; k0 < 256; k0 += 16) {
        stage_tile<32, 2>(A, 256, m0, k0, As, tid);
        stage_tile<32, 2>(W, 256, n0, k0, Ws, tid);
        __syncthreads();
        #pragma unroll
        for (int k = 0; k < 16; ++k) {
            float a0 = As[k * 33 + ty * 2], a1 = As[k * 33 + ty * 2 + 1];
            float w0 = Ws[k * 33 + tx * 2], w1 = Ws[k * 33 + tx * 2 + 1];
            acc[0][0] = fmaf(a0, w0, acc[0][0]);
            acc[0][1] = fmaf(a0, w1, acc[0][1]);
            acc[1][0] = fmaf(a1, w0, acc[1][0]);
            acc[1][1] = fmaf(a1, w1, acc[1][1]);
        }
        __syncthreads();
    }
    #pragma unroll
    for (int u = 0; u < 2; ++u) {
        int m = m0 + ty * 2 + u;
        #pragma unroll
        for (int v = 0; v < 2; ++v) {
            float o = acc[u][v] * sc;
            if (bias) o += bias[n0 + tx * 2 + v];
            C[(size_t)m * DMc + n0 + tx * 2 + v] = o;
        }
    }
}

// ===========================================================================
// k_pre: heterogeneous pre-work dispatch (all mutually independent roles):
//   [0,128)   tab   (table + narrow-list build for g_rel)
//   [128,192) gabs
//   [192,576) QKV gemm (3z x 16m x 8n tiles of 32x32)
// ===========================================================================
__global__ void __launch_bounds__(256) k_pre(
    const float* __restrict__ x, const float* __restrict__ t,
    const float* __restrict__ WQ, const float* __restrict__ WK, const float* __restrict__ WV,
    const float* __restrict__ mu_a, const float* __restrict__ sg_a, const float* __restrict__ w_a,
    const float* __restrict__ mu_r, const float* __restrict__ sg_r, const float* __restrict__ w_r,
    float* __restrict__ Qb, float* __restrict__ Kb, float* __restrict__ Vb,
    float* __restrict__ GA,
    float4* __restrict__ TAB, float4* __restrict__ NLIST, int* __restrict__ NCNT)
{
    __shared__ __align__(16) float smem[1056];
    int bx = blockIdx.x;
    if (bx < 128) {
        role_tab(bx, mu_r, sg_r, w_r, TAB, NLIST, NCNT, smem);
    } else if (bx < 192) {
        role_gabs(bx - 128, t, mu_a, sg_a, w_a, GA, smem);
    } else {
        int idx = bx - 192;           // 0..383
        int z = idx >> 7;             // 0:Q 1:K 2:V
        int r = idx & 127;
        int m0 = (r >> 3) * 32, n0 = (r & 7) * 32;
        const float* W = (z == 0) ? WQ : (z == 1) ? WK : WV;
        float* C = (z == 0) ? Qb : (z == 1) ? Kb : Vb;
        gemm32(x, W, C, nullptr, (z == 0) ? RSQRT_DH : 1.0f, m0, n0, smem);
    }
}

// ===========================================================================
// kB: S = Q@K^T (Q pre-scaled), P = X@X^T; 64x64 tiles, K=32. Fused
// modulation logit = S*(P*(2*alpha*g_abs + beta*g_rel)+gamma), in-place on GR.
// grid (4,4,16). [unchanged — proven]
// ===========================================================================
__global__ void __launch_bounds__(256) k_sp(
    const float* __restrict__ Q, const float* __restrict__ K, const float* __restrict__ x,
    const float* __restrict__ gabs,
    const float* __restrict__ alpha, const float* __restrict__ beta, const float* __restrict__ gamma,
    float* __restrict__ G)
{
    constexpr int PITCH = 68;
    int it = blockIdx.x, jt = blockIdx.y, bh = blockIdx.z;
    int b = bh >> 3, h = bh & 7;
    int i0 = it * 64, j0 = jt * 64;
    int tid = threadIdx.x;
    __shared__ float sm[4 * 32 * PITCH];
    float* sQ  = sm;
    float* sK  = sm + 32 * PITCH;
    float* sXi = sm + 64 * PITCH;
    float* sXj = sm + 96 * PITCH;

    int r0 = tid >> 3;
    int c4 = (tid & 7) * 4;
    #pragma unroll
    for (int uu = 0; uu < 2; ++uu) {
        int r = r0 + uu * 32;
        float4 qv = *(const float4*)(Q + ((size_t)(b * Lc + i0 + r) * DMc + h * DHc + c4));
        float4 kv = *(const float4*)(K + ((size_t)(b * Lc + j0 + r) * DMc + h * DHc + c4));
        float4 xi = *(const float4*)(x + ((size_t)(b * Lc + i0 + r) * DMc + h * DHc + c4));
        float4 xj = *(const float4*)(x + ((size_t)(b * Lc + j0 + r) * DMc + h * DHc + c4));
        const float* q_ = (const float*)&qv; const float* k_ = (const float*)&kv;
        const float* a_ = (const float*)&xi; const float* c_ = (const float*)&xj;
        #pragma unroll
        for (int u = 0; u < 4; ++u) {
            sQ [(c4 + u) * PITCH + r] = q_[u];
            sK [(c4 + u) * PITCH + r] = k_[u];
            sXi[(c4 + u) * PITCH + r] = a_[u];
            sXj[(c4 + u) * PITCH + r] = c_[u];
        }
    }
    __syncthreads();

    int tx = tid & 15, ty = tid >> 4;
    int i4 = ty * 4, j4 = tx * 4;
    float accS[4][4] = {}, accP[4][4] = {};
    #pragma unroll 4
    for (int k = 0; k < 32; ++k) {
        float4 qa = *(const float4*)(sQ  + k * PITCH + i4);
        float4 kb = *(const float4*)(sK  + k * PITCH + j4);
        float4 xa = *(const float4*)(sXi + k * PITCH + i4);
        float4 xb = *(const float4*)(sXj + k * PITCH + j4);
        const float* qa_ = (const float*)&qa; const float* kb_ = (const float*)&kb;
        const float* xa_ = (const float*)&xa; const float* xb_ = (const float*)&xb;
        #pragma unroll
        for (int u = 0; u < 4; ++u)
            #pragma unroll
            for (int v = 0; v < 4; ++v) {
                accS[u][v] = fmaf(qa_[u], kb_[v], accS[u][v]);
                accP[u][v] = fmaf(xa_[u], xb_[v], accP[u][v]);
            }
    }

    float la = alpha[h], lb = beta[h], lg = gamma[h];
    float* gb = G + (size_t)bh * (Lc * Lc);
    #pragma unroll
    for (int u = 0; u < 4; ++u) {
        int i = i0 + i4 + u;
        float gi2 = 2.0f * la * gabs[bh * Lc + i];
        float* addr = gb + (size_t)i * Lc + j0 + j4;
        float4 gr = *(const float4*)addr;
        float4 o;
        o.x = accS[u][0] * fmaf(accP[u][0], fmaf(lb, gr.x, gi2), lg);
        o.y = accS[u][1] * fmaf(accP[u][1], fmaf(lb, gr.y, gi2), lg);
        o.z = accS[u][2] * fmaf(accP[u][2], fmaf(lb, gr.z, gi2), lg);
        o.w = accS[u][3] * fmaf(accP[u][3], fmaf(lb, gr.w, gi2), lg);
        *(float4*)addr = o;
    }
}

// ===========================================================================
// kC: softmax fused into PV. grid (16 i-tiles, 16 bh), block 256. [unchanged]
// ===========================================================================
__global__ void __launch_bounds__(256) k_pvsm(const float* __restrict__ P,
                                              const float* __restrict__ V,
                                              float* __restrict__ AO) {
    int it = blockIdx.x, bh = blockIdx.y;
    int b = bh >> 3, h = bh & 7;
    int i0 = it * 16;
    int tid = threadIdx.x;
    __shared__ float sP[16 * 260];
    __shared__ float sV[256 * 34];
    int i = tid >> 4, l = tid & 15;

    const float* row = P + (size_t)bh * (Lc * Lc) + (size_t)(i0 + i) * Lc + l * 16;
    float4 p0 = *(const float4*)(row);
    float4 p1 = *(const float4*)(row + 4);
    float4 p2 = *(const float4*)(row + 8);
    float4 p3 = *(const float4*)(row + 12);
    float m = fmaxf(fmaxf(fmaxf(p0.x, p0.y), fmaxf(p0.z, p0.w)),
                    fmaxf(fmaxf(p1.x, p1.y), fmaxf(p1.z, p1.w)));
    m = fmaxf(m, fmaxf(fmaxf(fmaxf(p2.x, p2.y), fmaxf(p2.z, p2.w)),
                       fmaxf(fmaxf(p3.x, p3.y), fmaxf(p3.z, p3.w))));
    #pragma unroll
    for (int s = 1; s < 16; s <<= 1) m = fmaxf(m, __shfl_xor(m, s, 64));
    float4 e0, e1, e2, e3;
    e0.x = EXP2((p0.x - m) * LOG2E); e0.y = EXP2((p0.y - m) * LOG2E);
    e0.z = EXP2((p0.z - m) * LOG2E); e0.w = EXP2((p0.w - m) * LOG2E);
    e1.x = EXP2((p1.x - m) * LOG2E); e1.y = EXP2((p1.y - m) * LOG2E);
    e1.z = EXP2((p1.z - m) * LOG2E); e1.w = EXP2((p1.w - m) * LOG2E);
    e2.x = EXP2((p2.x - m) * LOG2E); e2.y = EXP2((p2.y - m) * LOG2E);
    e2.z = EXP2((p2.z - m) * LOG2E); e2.w = EXP2((p2.w - m) * LOG2E);
    e3.x = EXP2((p3.x - m) * LOG2E); e3.y = EXP2((p3.y - m) * LOG2E);
    e3.z = EXP2((p3.z - m) * LOG2E); e3.w = EXP2((p3.w - m) * LOG2E);
    float sum = ((e0.x + e0.y) + (e0.z + e0.w)) + ((e1.x + e1.y) + (e1.z + e1.w)) +
                ((e2.x + e2.y) + (e2.z + e2.w)) + ((e3.x + e3.y) + (e3.z + e3.w));
    #pragma unroll
    for (int s = 1; s < 16; s <<= 1) sum += __shfl_xor(sum, s, 64);
    float rs = 1.0f / sum;
    *(float4*)(sP + i * 260 + l * 16)      = e0;
    *(float4*)(sP + i * 260 + l * 16 + 4)  = e1;
    *(float4*)(sP + i * 260 + l * 16 + 8)  = e2;
    *(float4*)(sP + i * 260 + l * 16 + 12) = e3;

    int jj = tid >> 3, c4 = (tid & 7) * 4;
    #pragma unroll
    for (int u = 0; u < 8; ++u) {
        int j = jj + u * 32;
        *(float4*)(sV + j * 34 + c4) =
            *(const float4*)(V + ((size_t)(b * Lc + j) * DMc + h * DHc + c4));
    }
    __syncthreads();

    int d2 = l * 2;
    float o0 = 0.f, o1 = 0.f;
    #pragma unroll 2
    for (int j4 = 0; j4 < 256; j4 += 4) {
        float4 p4 = *(const float4*)(sP + i * 260 + j4);
        float2 v0 = *(const float2*)(sV + (j4 + 0) * 34 + d2);
        float2 v1 = *(const float2*)(sV + (j4 + 1) * 34 + d2);
        float2 v2 = *(const float2*)(sV + (j4 + 2) * 34 + d2);
        float2 v3 = *(const float2*)(sV + (j4 + 3) * 34 + d2);
        o0 += p4.x * v0.x + p4.y * v1.x + p4.z * v2.x + p4.w * v3.x;
        o1 += p4.x * v0.y + p4.y * v1.y + p4.z * v2.y + p4.w * v3.y;
    }
    *(float2*)(AO + ((size_t)(b * Lc + i0 + i) * DMc + h * DHc + d2)) =
        make_float2(o0 * rs, o1 * rs);
}

// ===========================================================================
// kD: out = AO @ WO^T + bO.  grid (16,8), 32x32 tiles. [unchanged]
// ===========================================================================
__global__ void __launch_bounds__(256) k_out(const float* __restrict__ A,
                                             const float* __restrict__ W,
                                             const float* __restrict__ bias,
                                             float* __restrict__ C) {
    __shared__ float smem[2 * 16 * 33];
    gemm32(A, W, C, bias, 1.0f, blockIdx.x * 32, blockIdx.y * 32, smem);
}

// ===========================================================================
extern "C" void kernel_launch(void* const* d_in, const int* in_sizes, int n_in,
                              void* d_out, int out_size, void* d_ws, size_t ws_size,
                              hipStream_t stream) {
    (void)in_sizes; (void)n_in; (void)out_size; (void)ws_size;
    const float* x      = (const float*)d_in[0];
    const float* t      = (const float*)d_in[1];
    const float* WQ     = (const float*)d_in[2];
    const float* WK     = (const float*)d_in[3];
    const float* WV     = (const float*)d_in[4];
    const float* WO     = (const float*)d_in[5];
    const float* bO     = (const float*)d_in[6];
    const float* mu_abs = (const float*)d_in[7];
    const float* sg_abs = (const float*)d_in[8];
    const float* w_abs  = (const float*)d_in[9];
    const float* mu_rel = (const float*)d_in[10];
    const float* sg_rel = (const float*)d_in[11];
    const float* w_rel  = (const float*)d_in[12];
    const float* alpha  = (const float*)d_in[13];
    const float* beta   = (const float*)d_in[14];
    const float* gamma  = (const float*)d_in[15];
    float* out = (float*)d_out;
    float* ws = (float*)d_ws;

    float* Qb = ws;                // 131072 floats
    float* Kb = ws + 131072;
    float* Vb = ws + 262144;
    float* AO = ws + 393216;
    float* GA = ws + 524288;       // 4096
    float* GR = ws + 528384;       // 1048576 (g_rel -> logits)
    float4* TAB   = (float4*)(ws + 1576960);   // 32 x 512 x float4
    float4* NLIST = (float4*)(ws + 1642496);   // 32 x 128 x float4
    int*    NCNT  = (int*)   (ws + 1658880);   // 32 ints

    k_pre<<<dim3(576), dim3(256), 0, stream>>>(x, t, WQ, WK, WV,
                                               mu_abs, sg_abs, w_abs,
                                               mu_rel, sg_rel, w_rel,
                                               Qb, Kb, Vb, GA, TAB, NLIST, NCNT);
    k_gauss<<<dim3(272), dim3(256), 0, stream>>>(t, TAB, NLIST, NCNT, GR);
    k_sp<<<dim3(4, 4, 16), dim3(256), 0, stream>>>(Qb, Kb, x, GA, alpha, beta, gamma, GR);
    k_pvsm<<<dim3(16, 16), dim3(256), 0, stream>>>(GR, Vb, AO);
    k_out<<<dim3(16, 8), dim3(256), 0, stream>>>(AO, WO, bO, out);
}

// Round 3
// 136.359 us; speedup vs baseline: 1.1807x; 1.0802x over previous
//
#include <hip/hip_runtime.h>
#include <math.h>

constexpr int Bc = 2, Lc = 256, DMc = 256, Hc = 8, DHc = 32;
constexpr float LOG2E = 1.4426950408889634f;
constexpr float RSQRT_DH = 0.17677669529663687f; // 1/sqrt(32)
#define EXP2 __builtin_amdgcn_exp2f

// Gaussian-mixture tabulation parameters (see R0 notes).
constexpr int   NTAB = 512;
constexpr float SIG0 = 0.08f;

// ===========================================================================
// role_tab: build per-(h,tau) piecewise-quadratic tables + narrow lists.
// 128 blocks = 32 (h,tau) x 4 chunks. Parallel narrow-list compaction.
// ===========================================================================
__device__ __forceinline__ float mixsum(const float4* __restrict__ prm, float x) {
    float acc = 0.f;
    #pragma unroll 8
    for (int q = 0; q < 128; ++q) {
        float4 p = prm[q];          // (mu, n, w_masked, 0), wave-uniform ds_read
        float d0 = x - p.x;
        acc = fmaf(p.z, EXP2(d0 * d0 * p.y), acc);
    }
    return acc;
}

__device__ __forceinline__ void role_tab(int bx,
    const float* __restrict__ mu, const float* __restrict__ sg, const float* __restrict__ w,
    float4* __restrict__ TAB, float4* __restrict__ NLIST, int* __restrict__ NCNT,
    float* smem)
{
    float4* prm = (float4*)smem;      // 128 float4 = 512 floats
    float*  fs  = smem + 512;         // 260 floats
    int*    lcnt = (int*)(smem + 772);
    int hm = bx >> 2, chunk = bx & 3;      // hm = h*4+tau
    int h = hm >> 2, tau = hm & 3;
    int tid = threadIdx.x;

    if (tid == 0) *lcnt = 0;
    __syncthreads();
    if (tid < 128) {
        int d = tid >> 2, k = tid & 3;
        int off = h * 512 + d * 16 + tau * 4 + k;
        float s  = sg[off];
        float mv = mu[off], wv = w[off];
        float n = -(0.5f * LOG2E) / (s * s);
        bool narrow = (s < SIG0);
        prm[tid] = make_float4(mv, n, narrow ? 0.0f : wv, 0.0f);
        if (chunk == 0 && narrow) {
            int slot = atomicAdd(lcnt, 1);      // order irrelevant: summed later
            NLIST[hm * 128 + slot] = make_float4(mv, n, wv, 0.0f);
        }
    }
    __syncthreads();
    if (chunk == 0 && tid == 0) NCNT[hm] = *lcnt;

    // samples at x = (chunk*256 + s)/1024, s = 0..256
    fs[tid] = mixsum(prm, (float)(chunk * 256 + tid) * (1.0f / 1024.0f));
    if (tid == 0)
        fs[256] = mixsum(prm, (float)(chunk * 256 + 256) * (1.0f / 1024.0f));
    __syncthreads();

    if (tid < 128) {
        float f0 = fs[tid * 2], fm = fs[tid * 2 + 1], f1 = fs[tid * 2 + 2];
        float c2 = 2.0f * (f0 + f1 - 2.0f * fm);
        float c1 = f1 - f0 - c2;
        TAB[hm * NTAB + chunk * 128 + tid] = make_float4(f0, c1, c2, 0.0f);
    }
}

// ===========================================================================
// k_gauss: g_rel via table lookup + exact narrow residual.
// grid 544 = 16 (b,h) x 34 chunks; 4 sym tile-pairs per block (was 8 over 272
// blocks = 1.06 blk/CU; now 2.1 blk/CU so LDS gather latency is covered).
// ===========================================================================
__global__ void __launch_bounds__(256) k_gauss(
    const float* __restrict__ t, const float4* __restrict__ TAB,
    const float4* __restrict__ NLIST, const int* __restrict__ NCNT,
    float* __restrict__ GR)
{
    __shared__ float4 tab[4 * NTAB];     // 32 KB
    __shared__ float lt[16 * 17];
    int bx = blockIdx.x;
    int bh = bx / 34, chunk = bx - bh * 34;
    int b = bh >> 3, h = bh & 7;
    int tid = threadIdx.x;

    const float4* src = TAB + h * 4 * NTAB;
    #pragma unroll
    for (int u = 0; u < (4 * NTAB) / 256; ++u)
        tab[tid + u * 256] = src[tid + u * 256];
    int cnt[4];
    #pragma unroll
    for (int tg = 0; tg < 4; ++tg) cnt[tg] = NCNT[h * 4 + tg];
    __syncthreads();

    float* gb = GR + (size_t)bh * (Lc * Lc);
    int di = tid >> 4, dj = tid & 15;

    for (int pi = 0; pi < 4; ++pi) {
        int p = chunk * 4 + pi;          // 0..135, block-uniform
        int ti = 0, pp = p;
        for (;; ++ti) { int c = 16 - ti; if (pp < c) break; pp -= c; }
        int tj = ti + pp;
        int i = ti * 16 + di, j = tj * 16 + dj;
        float4 t_i = *(const float4*)(t + (b * Lc + i) * 4);
        float4 t_j = *(const float4*)(t + (b * Lc + j) * 4);
        float tr[4] = {fabsf(t_i.x - t_j.x), fabsf(t_i.y - t_j.y),
                       fabsf(t_i.z - t_j.z), fabsf(t_i.w - t_j.w)};
        float g = 0.f;
        #pragma unroll
        for (int tg = 0; tg < 4; ++tg) {
            float x = tr[tg];
            float xs = x * (float)NTAB;
            int iu = (int)xs; iu = min(iu, NTAB - 1);
            float uu = xs - (float)iu;
            float4 c = tab[tg * NTAB + iu];                 // per-lane gather
            float val = fmaf(uu, fmaf(uu, c.z, c.y), c.x);  // table part
            int cn = cnt[tg];                               // wave-uniform trip count
            for (int nn = 0; nn < cn; ++nn) {
                float4 q = NLIST[(h * 4 + tg) * 128 + nn];  // uniform -> s_load
                float d0 = x - q.x;
                val = fmaf(q.z, EXP2(d0 * d0 * q.y), val);  // exact narrow part
            }
            g += val;
        }
        g *= (1.0f / 32.0f);
        gb[i * Lc + j] = g;
        if (ti != tj) {                  // block-uniform branch: syncs are safe
            __syncthreads();             // protect lt reuse across pairs
            lt[di * 17 + dj] = g;
            __syncthreads();
            gb[(tj * 16 + di) * Lc + (ti * 16 + dj)] = lt[dj * 17 + di];
        }
    }
}

// ===========================================================================
// role_gabs (exact): only 64 blocks — not worth tabulating. [unchanged]
// ===========================================================================
__device__ __forceinline__ void role_gabs(int idx, const float* __restrict__ t,
                                          const float* __restrict__ mu, const float* __restrict__ sg,
                                          const float* __restrict__ w, float* __restrict__ gabs,
                                          float* smem) {
    int h = idx & 7, b = (idx >> 3) & 1, q = idx >> 4;   // q: i-quarter
    int tid = threadIdx.x;
    {
        float2 s2 = *(const float2*)(sg + h * 512 + tid * 2);
        float2 o;
        o.x = -(0.5f * LOG2E) / (s2.x * s2.x);
        o.y = -(0.5f * LOG2E) / (s2.y * s2.y);
        *(float2*)(smem + tid * 2) = o;
    }
    __syncthreads();
    int lane = tid & 63, tg = tid >> 6;
    int i = q * 64 + lane;
    float tv = t[(b * Lc + i) * 4 + tg];
    const float* muB = mu + h * 512 + tg * 4;
    const float* wB  = w  + h * 512 + tg * 4;
    const float* nsB = smem + tg * 4;
    float acc = 0.f;
    #pragma unroll 4
    for (int d = 0; d < 32; ++d) {
        float4 m4 = *(const float4*)(muB + d * 16);
        float4 w4 = *(const float4*)(wB  + d * 16);
        float4 n4 = *(const float4*)(nsB + d * 16);
        float d0 = tv - m4.x; acc = fmaf(w4.x, EXP2(d0 * d0 * n4.x), acc);
        float d1 = tv - m4.y; acc = fmaf(w4.y, EXP2(d1 * d1 * n4.y), acc);
        float d2 = tv - m4.z; acc = fmaf(w4.z, EXP2(d2 * d2 * n4.z), acc);
        float d3 = tv - m4.w; acc = fmaf(w4.w, EXP2(d3 * d3 * n4.w), acc);
    }
    float* red = smem + 512;   // 4 x 64
    red[tg * 64 + lane] = acc;
    __syncthreads();
    if (tid < 64)
        gabs[(b * Hc + h) * Lc + q * 64 + lane] =
            (red[lane] + red[64 + lane] + red[128 + lane] + red[192 + lane]) * (1.0f / 32.0f);
}

template<int R>
__device__ __forceinline__ void stage_tile2(const float* __restrict__ src, int ld,
                                            int row0, int k0, float* __restrict__ dst, int tid) {
    int row = tid >> 3;
    int cb = (tid & 7) * 2;
    float2 v = *(const float2*)(src + (size_t)(row0 + row) * ld + k0 + cb);
    dst[(cb + 0) * (R + 1) + row] = v.x;
    dst[(cb + 1) * (R + 1) + row] = v.y;
}

__device__ __forceinline__ void gemm32(const float* __restrict__ A, const float* __restrict__ W,
                                       float* __restrict__ C, const float* __restrict__ bias,
                                       float sc, int m0, int n0, float* smem) {
    // C[m0:+32, n0:+32] = sc * A[.,K=256] @ W^T (+bias); LDS [k][m] pitch 33.
    float* As = smem;
    float* Ws = smem + 16 * 33;
    int tid = threadIdx.x;
    int tx = tid & 15, ty = tid >> 4;
    float acc[2][2] = {};
    for (int k0 = 0; k0 < 256; k0 += 16) {
        stage_tile2<32>(A, 256, m0, k0, As, tid);
        stage_tile2<32>(W, 256, n0, k0, Ws, tid);
        __syncthreads();
        #pragma unroll
        for (int k = 0; k < 16; ++k) {
            float a0 = As[k * 33 + ty * 2], a1 = As[k * 33 + ty * 2 + 1];
            float w0 = Ws[k * 33 + tx * 2], w1 = Ws[k * 33 + tx * 2 + 1];
            acc[0][0] = fmaf(a0, w0, acc[0][0]);
            acc[0][1] = fmaf(a0, w1, acc[0][1]);
            acc[1][0] = fmaf(a1, w0, acc[1][0]);
            acc[1][1] = fmaf(a1, w1, acc[1][1]);
        }
        __syncthreads();
    }
    #pragma unroll
    for (int u = 0; u < 2; ++u) {
        int m = m0 + ty * 2 + u;
        #pragma unroll
        for (int v = 0; v < 2; ++v) {
            float o = acc[u][v] * sc;
            if (bias) o += bias[n0 + tx * 2 + v];
            C[(size_t)m * DMc + n0 + tx * 2 + v] = o;
        }
    }
}

// ===========================================================================
// k_pre: heterogeneous pre-work dispatch:
//   [0,128)   tab, [128,192) gabs, [192,576) QKV gemm
// ===========================================================================
__global__ void __launch_bounds__(256) k_pre(
    const float* __restrict__ x, const float* __restrict__ t,
    const float* __restrict__ WQ, const float* __restrict__ WK, const float* __restrict__ WV,
    const float* __restrict__ mu_a, const float* __restrict__ sg_a, const float* __restrict__ w_a,
    const float* __restrict__ mu_r, const float* __restrict__ sg_r, const float* __restrict__ w_r,
    float* __restrict__ Qb, float* __restrict__ Kb, float* __restrict__ Vb,
    float* __restrict__ GA,
    float4* __restrict__ TAB, float4* __restrict__ NLIST, int* __restrict__ NCNT)
{
    __shared__ __align__(16) float smem[1056];
    int bx = blockIdx.x;
    if (bx < 128) {
        role_tab(bx, mu_r, sg_r, w_r, TAB, NLIST, NCNT, smem);
    } else if (bx < 192) {
        role_gabs(bx - 128, t, mu_a, sg_a, w_a, GA, smem);
    } else {
        int idx = bx - 192;           // 0..383
        int z = idx >> 7;             // 0:Q 1:K 2:V
        int r = idx & 127;
        int m0 = (r >> 3) * 32, n0 = (r & 7) * 32;
        const float* W = (z == 0) ? WQ : (z == 1) ? WK : WV;
        float* C = (z == 0) ? Qb : (z == 1) ? Kb : Vb;
        gemm32(x, W, C, nullptr, (z == 0) ? RSQRT_DH : 1.0f, m0, n0, smem);
    }
}

// ===========================================================================
// kB: S = Q@K^T (Q pre-scaled), P = X@X^T; 64x64 tiles, K=32. Fused
// modulation logit = S*(P*(2*alpha*g_abs + beta*g_rel)+gamma), in-place on GR.
// grid (4,4,16), block 512 (was 256): 2 waves/SIMD to hide LDS latency;
// per-thread output 2x4 (was 4x4), same FMA order per output.
// ===========================================================================
__global__ void __launch_bounds__(512) k_sp(
    const float* __restrict__ Q, const float* __restrict__ K, const float* __restrict__ x,
    const float* __restrict__ gabs,
    const float* __restrict__ alpha, const float* __restrict__ beta, const float* __restrict__ gamma,
    float* __restrict__ G)
{
    constexpr int PITCH = 68;
    int it = blockIdx.x, jt = blockIdx.y, bh = blockIdx.z;
    int b = bh >> 3, h = bh & 7;
    int i0 = it * 64, j0 = jt * 64;
    int tid = threadIdx.x;
    __shared__ float sm[4 * 32 * PITCH];
    float* sQ  = sm;
    float* sK  = sm + 32 * PITCH;
    float* sXi = sm + 64 * PITCH;
    float* sXj = sm + 96 * PITCH;

    {   // 512 threads: each stages one float4 per array (64 rows x 32 cols)
        int r = tid >> 3;
        int c4 = (tid & 7) * 4;
        float4 qv = *(const float4*)(Q + ((size_t)(b * Lc + i0 + r) * DMc + h * DHc + c4));
        float4 kv = *(const float4*)(K + ((size_t)(b * Lc + j0 + r) * DMc + h * DHc + c4));
        float4 xi = *(const float4*)(x + ((size_t)(b * Lc + i0 + r) * DMc + h * DHc + c4));
        float4 xj = *(const float4*)(x + ((size_t)(b * Lc + j0 + r) * DMc + h * DHc + c4));
        const float* q_ = (const float*)&qv; const float* k_ = (const float*)&kv;
        const float* a_ = (const float*)&xi; const float* c_ = (const float*)&xj;
        #pragma unroll
        for (int u = 0; u < 4; ++u) {
            sQ [(c4 + u) * PITCH + r] = q_[u];
            sK [(c4 + u) * PITCH + r] = k_[u];
            sXi[(c4 + u) * PITCH + r] = a_[u];
            sXj[(c4 + u) * PITCH + r] = c_[u];
        }
    }
    __syncthreads();

    int tx = tid & 15, ty = tid >> 4;    // ty in [0,32)
    int i2 = ty * 2, j4 = tx * 4;
    float accS[2][4] = {}, accP[2][4] = {};
    #pragma unroll 4
    for (int k = 0; k < 32; ++k) {
        float2 qa = *(const float2*)(sQ  + k * PITCH + i2);
        float4 kb = *(const float4*)(sK  + k * PITCH + j4);
        float2 xa = *(const float2*)(sXi + k * PITCH + i2);
        float4 xb = *(const float4*)(sXj + k * PITCH + j4);
        const float* qa_ = (const float*)&qa; const float* kb_ = (const float*)&kb;
        const float* xa_ = (const float*)&xa; const float* xb_ = (const float*)&xb;
        #pragma unroll
        for (int u = 0; u < 2; ++u)
            #pragma unroll
            for (int v = 0; v < 4; ++v) {
                accS[u][v] = fmaf(qa_[u], kb_[v], accS[u][v]);
                accP[u][v] = fmaf(xa_[u], xb_[v], accP[u][v]);
            }
    }

    float la = alpha[h], lb = beta[h], lg = gamma[h];
    float* gb = G + (size_t)bh * (Lc * Lc);
    #pragma unroll
    for (int u = 0; u < 2; ++u) {
        int i = i0 + i2 + u;
        float gi2 = 2.0f * la * gabs[bh * Lc + i];
        float* addr = gb + (size_t)i * Lc + j0 + j4;
        float4 gr = *(const float4*)addr;
        float4 o;
        o.x = accS[u][0] * fmaf(accP[u][0], fmaf(lb, gr.x, gi2), lg);
        o.y = accS[u][1] * fmaf(accP[u][1], fmaf(lb, gr.y, gi2), lg);
        o.z = accS[u][2] * fmaf(accP[u][2], fmaf(lb, gr.z, gi2), lg);
        o.w = accS[u][3] * fmaf(accP[u][3], fmaf(lb, gr.w, gi2), lg);
        *(float4*)addr = o;
    }
}

// ===========================================================================
// kC: softmax fused into PV. grid (16,16), block 512 (was 256): 2 waves/SIMD.
// Pass1: thread (i=tid>>5, l=tid&31) loads 8 logits, 32-lane-group shuffle
// max/sum. Pass2: PV, one d-column per thread.
// ===========================================================================
__global__ void __launch_bounds__(512) k_pvsm(const float* __restrict__ P,
                                              const float* __restrict__ V,
                                              float* __restrict__ AO) {
    int it = blockIdx.x, bh = blockIdx.y;
    int b = bh >> 3, h = bh & 7;
    int i0 = it * 16;
    int tid = threadIdx.x;
    __shared__ float sP[16 * 260];
    __shared__ float sV[256 * 34];
    int i = tid >> 5, l = tid & 31;

    const float* row = P + (size_t)bh * (Lc * Lc) + (size_t)(i0 + i) * Lc + l * 8;
    float4 p0 = *(const float4*)(row);
    float4 p1 = *(const float4*)(row + 4);
    float m = fmaxf(fmaxf(fmaxf(p0.x, p0.y), fmaxf(p0.z, p0.w)),
                    fmaxf(fmaxf(p1.x, p1.y), fmaxf(p1.z, p1.w)));
    #pragma unroll
    for (int s = 1; s < 32; s <<= 1) m = fmaxf(m, __shfl_xor(m, s, 32));
    float4 e0, e1;
    e0.x = EXP2((p0.x - m) * LOG2E); e0.y = EXP2((p0.y - m) * LOG2E);
    e0.z = EXP2((p0.z - m) * LOG2E); e0.w = EXP2((p0.w - m) * LOG2E);
    e1.x = EXP2((p1.x - m) * LOG2E); e1.y = EXP2((p1.y - m) * LOG2E);
    e1.z = EXP2((p1.z - m) * LOG2E); e1.w = EXP2((p1.w - m) * LOG2E);
    float sum = ((e0.x + e0.y) + (e0.z + e0.w)) + ((e1.x + e1.y) + (e1.z + e1.w));
    #pragma unroll
    for (int s = 1; s < 32; s <<= 1) sum += __shfl_xor(sum, s, 32);
    float rs = 1.0f / sum;
    *(float4*)(sP + i * 260 + l * 8)     = e0;
    *(float4*)(sP + i * 260 + l * 8 + 4) = e1;

    {   // stage V: 512 threads x 4 rows x float4
        int jr = tid >> 3, c4 = (tid & 7) * 4;
        #pragma unroll
        for (int u = 0; u < 4; ++u) {
            int j = jr + u * 64;
            *(float4*)(sV + j * 34 + c4) =
                *(const float4*)(V + ((size_t)(b * Lc + j) * DMc + h * DHc + c4));
        }
    }
    __syncthreads();

    int d = l;                  // one output column per thread
    float o0 = 0.f;
    #pragma unroll 4
    for (int j4 = 0; j4 < 256; j4 += 4) {
        float4 p4 = *(const float4*)(sP + i * 260 + j4);
        float v0 = sV[(j4 + 0) * 34 + d];
        float v1 = sV[(j4 + 1) * 34 + d];
        float v2 = sV[(j4 + 2) * 34 + d];
        float v3 = sV[(j4 + 3) * 34 + d];
        o0 = fmaf(p4.x, v0, o0); o0 = fmaf(p4.y, v1, o0);
        o0 = fmaf(p4.z, v2, o0); o0 = fmaf(p4.w, v3, o0);
    }
    AO[((size_t)(b * Lc + i0 + i) * DMc + h * DHc + d)] = o0 * rs;
}

// ===========================================================================
// kD: out = AO @ WO^T + bO.  grid (16,8), 32x32 tiles. [unchanged]
// ===========================================================================
__global__ void __launch_bounds__(256) k_out(const float* __restrict__ A,
                                             const float* __restrict__ W,
                                             const float* __restrict__ bias,
                                             float* __restrict__ C) {
    __shared__ float smem[2 * 16 * 33];
    gemm32(A, W, C, bias, 1.0f, blockIdx.x * 32, blockIdx.y * 32, smem);
}

// ===========================================================================
extern "C" void kernel_launch(void* const* d_in, const int* in_sizes, int n_in,
                              void* d_out, int out_size, void* d_ws, size_t ws_size,
                              hipStream_t stream) {
    (void)in_sizes; (void)n_in; (void)out_size; (void)ws_size;
    const float* x      = (const float*)d_in[0];
    const float* t      = (const float*)d_in[1];
    const float* WQ     = (const float*)d_in[2];
    const float* WK     = (const float*)d_in[3];
    const float* WV     = (const float*)d_in[4];
    const float* WO     = (const float*)d_in[5];
    const float* bO     = (const float*)d_in[6];
    const float* mu_abs = (const float*)d_in[7];
    const float* sg_abs = (const float*)d_in[8];
    const float* w_abs  = (const float*)d_in[9];
    const float* mu_rel = (const float*)d_in[10];
    const float* sg_rel = (const float*)d_in[11];
    const float* w_rel  = (const float*)d_in[12];
    const float* alpha  = (const float*)d_in[13];
    const float* beta   = (const float*)d_in[14];
    const float* gamma  = (const float*)d_in[15];
    float* out = (float*)d_out;
    float* ws = (float*)d_ws;

    float* Qb = ws;                // 131072 floats
    float* Kb = ws + 131072;
    float* Vb = ws + 262144;
    float* AO = ws + 393216;
    float* GA = ws + 524288;       // 4096
    float* GR = ws + 528384;       // 1048576 (g_rel -> logits)
    float4* TAB   = (float4*)(ws + 1576960);   // 32 x 512 x float4
    float4* NLIST = (float4*)(ws + 1642496);   // 32 x 128 x float4
    int*    NCNT  = (int*)   (ws + 1658880);   // 32 ints

    k_pre<<<dim3(576), dim3(256), 0, stream>>>(x, t, WQ, WK, WV,
                                               mu_abs, sg_abs, w_abs,
                                               mu_rel, sg_rel, w_rel,
                                               Qb, Kb, Vb, GA, TAB, NLIST, NCNT);
    k_gauss<<<dim3(544), dim3(256), 0, stream>>>(t, TAB, NLIST, NCNT, GR);
    k_sp<<<dim3(4, 4, 16), dim3(512), 0, stream>>>(Qb, Kb, x, GA, alpha, beta, gamma, GR);
    k_pvsm<<<dim3(16, 16), dim3(512), 0, stream>>>(GR, Vb, AO);
    k_out<<<dim3(16, 8), dim3(256), 0, stream>>>(AO, WO, bO, out);
}

// Round 5
// 124.720 us; speedup vs baseline: 1.2909x; 1.0933x over previous
//
#include <hip/hip_runtime.h>
#include <math.h>

constexpr int Bc = 2, Lc = 256, DMc = 256, Hc = 8, DHc = 32;
constexpr float LOG2E = 1.4426950408889634f;
constexpr float RSQRT_DH = 0.17677669529663687f; // 1/sqrt(32)
#define EXP2 __builtin_amdgcn_exp2f

// Gaussian-mixture tabulation parameters.
// Piecewise-quadratic table over x in [0,1), 512 intervals (samples at 1/1024).
// sg < SIG0 excluded from table (kept exact in narrow list). At SIG0=0.02 the
// interp error is ~1e-5*|w| (0.088*(h/sigma)^3), and E[narrow count] ~ 2.
constexpr int   NTAB = 512;
constexpr float SIG0 = 0.02f;

// ===========================================================================
// role_tab: build per-(h,tau) piecewise-quadratic tables + narrow lists.
// 128 blocks = 32 (h,tau) x 4 chunks. Parallel narrow-list compaction.
// ===========================================================================
__device__ __forceinline__ float mixsum(const float4* __restrict__ prm, float x) {
    float acc = 0.f;
    #pragma unroll 8
    for (int q = 0; q < 128; ++q) {
        float4 p = prm[q];          // (mu, n, w_masked, 0), wave-uniform ds_read
        float d0 = x - p.x;
        acc = fmaf(p.z, EXP2(d0 * d0 * p.y), acc);
    }
    return acc;
}

__device__ __forceinline__ void role_tab(int bx,
    const float* __restrict__ mu, const float* __restrict__ sg, const float* __restrict__ w,
    float4* __restrict__ TAB, float4* __restrict__ NLIST, int* __restrict__ NCNT,
    float* smem)
{
    float4* prm = (float4*)smem;      // 128 float4 = 512 floats
    float*  fs  = smem + 512;         // 260 floats
    int*    lcnt = (int*)(smem + 772);
    int hm = bx >> 2, chunk = bx & 3;      // hm = h*4+tau
    int h = hm >> 2, tau = hm & 3;
    int tid = threadIdx.x;

    if (tid == 0) *lcnt = 0;
    __syncthreads();
    if (tid < 128) {
        int d = tid >> 2, k = tid & 3;
        int off = h * 512 + d * 16 + tau * 4 + k;
        float s  = sg[off];
        float mv = mu[off], wv = w[off];
        float n = -(0.5f * LOG2E) / (s * s);
        bool narrow = (s < SIG0);
        prm[tid] = make_float4(mv, n, narrow ? 0.0f : wv, 0.0f);
        if (chunk == 0 && narrow) {
            int slot = atomicAdd(lcnt, 1);      // order irrelevant: summed later
            NLIST[hm * 128 + slot] = make_float4(mv, n, wv, 0.0f);
        }
    }
    __syncthreads();
    if (chunk == 0 && tid == 0) NCNT[hm] = *lcnt;

    // samples at x = (chunk*256 + s)/1024, s = 0..256
    fs[tid] = mixsum(prm, (float)(chunk * 256 + tid) * (1.0f / 1024.0f));
    if (tid == 0)
        fs[256] = mixsum(prm, (float)(chunk * 256 + 256) * (1.0f / 1024.0f));
    __syncthreads();

    if (tid < 128) {
        float f0 = fs[tid * 2], fm = fs[tid * 2 + 1], f1 = fs[tid * 2 + 2];
        float c2 = 2.0f * (f0 + f1 - 2.0f * fm);
        float c1 = f1 - f0 - c2;
        TAB[hm * NTAB + chunk * 128 + tid] = make_float4(f0, c1, c2, 0.0f);
    }
}

// ===========================================================================
// role_gabs (exact): only 64 block-instances — not worth tabulating.
// ===========================================================================
__device__ __forceinline__ void role_gabs(int idx, const float* __restrict__ t,
                                          const float* __restrict__ mu, const float* __restrict__ sg,
                                          const float* __restrict__ w, float* __restrict__ gabs,
                                          float* smem) {
    int h = idx & 7, b = (idx >> 3) & 1, q = idx >> 4;   // q: i-quarter
    int tid = threadIdx.x;
    {
        float2 s2 = *(const float2*)(sg + h * 512 + tid * 2);
        float2 o;
        o.x = -(0.5f * LOG2E) / (s2.x * s2.x);
        o.y = -(0.5f * LOG2E) / (s2.y * s2.y);
        *(float2*)(smem + tid * 2) = o;
    }
    __syncthreads();
    int lane = tid & 63, tg = tid >> 6;
    int i = q * 64 + lane;
    float tv = t[(b * Lc + i) * 4 + tg];
    const float* muB = mu + h * 512 + tg * 4;
    const float* wB  = w  + h * 512 + tg * 4;
    const float* nsB = smem + tg * 4;
    float acc = 0.f;
    #pragma unroll 4
    for (int d = 0; d < 32; ++d) {
        float4 m4 = *(const float4*)(muB + d * 16);
        float4 w4 = *(const float4*)(wB  + d * 16);
        float4 n4 = *(const float4*)(nsB + d * 16);
        float d0 = tv - m4.x; acc = fmaf(w4.x, EXP2(d0 * d0 * n4.x), acc);
        float d1 = tv - m4.y; acc = fmaf(w4.y, EXP2(d1 * d1 * n4.y), acc);
        float d2 = tv - m4.z; acc = fmaf(w4.z, EXP2(d2 * d2 * n4.z), acc);
        float d3 = tv - m4.w; acc = fmaf(w4.w, EXP2(d3 * d3 * n4.w), acc);
    }
    float* red = smem + 512;   // 4 x 64
    red[tg * 64 + lane] = acc;
    __syncthreads();
    if (tid < 64)
        gabs[(b * Hc + h) * Lc + q * 64 + lane] =
            (red[lane] + red[64 + lane] + red[128 + lane] + red[192 + lane]) * (1.0f / 32.0f);
}

template<int R>
__device__ __forceinline__ void stage_tile2(const float* __restrict__ src, int ld,
                                            int row0, int k0, float* __restrict__ dst, int tid) {
    int row = tid >> 3;
    int cb = (tid & 7) * 2;
    float2 v = *(const float2*)(src + (size_t)(row0 + row) * ld + k0 + cb);
    dst[(cb + 0) * (R + 1) + row] = v.x;
    dst[(cb + 1) * (R + 1) + row] = v.y;
}

__device__ __forceinline__ void gemm32(const float* __restrict__ A, const float* __restrict__ W,
                                       float* __restrict__ C, const float* __restrict__ bias,
                                       float sc, int m0, int n0, float* smem) {
    // C[m0:+32, n0:+32] = sc * A[.,K=256] @ W^T (+bias); LDS [k][m] pitch 33.
    float* As = smem;
    float* Ws = smem + 16 * 33;
    int tid = threadIdx.x;
    int tx = tid & 15, ty = tid >> 4;
    float acc[2][2] = {};
    for (int k0 = 0; k0 < 256; k0 += 16) {
        stage_tile2<32>(A, 256, m0, k0, As, tid);
        stage_tile2<32>(W, 256, n0, k0, Ws, tid);
        __syncthreads();
        #pragma unroll
        for (int k = 0; k < 16; ++k) {
            float a0 = As[k * 33 + ty * 2], a1 = As[k * 33 + ty * 2 + 1];
            float w0 = Ws[k * 33 + tx * 2], w1 = Ws[k * 33 + tx * 2 + 1];
            acc[0][0] = fmaf(a0, w0, acc[0][0]);
            acc[0][1] = fmaf(a0, w1, acc[0][1]);
            acc[1][0] = fmaf(a1, w0, acc[1][0]);
            acc[1][1] = fmaf(a1, w1, acc[1][1]);
        }
        __syncthreads();
    }
    #pragma unroll
    for (int u = 0; u < 2; ++u) {
        int m = m0 + ty * 2 + u;
        #pragma unroll
        for (int v = 0; v < 2; ++v) {
            float o = acc[u][v] * sc;
            if (bias) o += bias[n0 + tx * 2 + v];
            C[(size_t)m * DMc + n0 + tx * 2 + v] = o;
        }
    }
}

// ===========================================================================
// k_pre: heterogeneous pre-work dispatch:
//   [0,128)   tab, [128,192) gabs, [192,576) QKV gemm
// ===========================================================================
__global__ void __launch_bounds__(256) k_pre(
    const float* __restrict__ x, const float* __restrict__ t,
    const float* __restrict__ WQ, const float* __restrict__ WK, const float* __restrict__ WV,
    const float* __restrict__ mu_a, const float* __restrict__ sg_a, const float* __restrict__ w_a,
    const float* __restrict__ mu_r, const float* __restrict__ sg_r, const float* __restrict__ w_r,
    float* __restrict__ Qb, float* __restrict__ Kb, float* __restrict__ Vb,
    float* __restrict__ GA,
    float4* __restrict__ TAB, float4* __restrict__ NLIST, int* __restrict__ NCNT)
{
    __shared__ __align__(16) float smem[1056];
    int bx = blockIdx.x;
    if (bx < 128) {
        role_tab(bx, mu_r, sg_r, w_r, TAB, NLIST, NCNT, smem);
    } else if (bx < 192) {
        role_gabs(bx - 128, t, mu_a, sg_a, w_a, GA, smem);
    } else {
        int idx = bx - 192;           // 0..383
        int z = idx >> 7;             // 0:Q 1:K 2:V
        int r = idx & 127;
        int m0 = (r >> 3) * 32, n0 = (r & 7) * 32;
        const float* W = (z == 0) ? WQ : (z == 1) ? WK : WV;
        float* C = (z == 0) ? Qb : (z == 1) ? Kb : Vb;
        gemm32(x, W, C, nullptr, (z == 0) ? RSQRT_DH : 1.0f, m0, n0, smem);
    }
}

// ===========================================================================
// kB: S = Q@K^T (Q pre-scaled), P = X@X^T; 64x64 tiles, K=32; grid (4,4,16),
// block 512. g_rel computed IN the epilogue from the per-head table (staged
// into the SAME LDS after the MM loop — tile buffers are dead by then).
// Replaces the separate k_gauss dispatch + 8 MB of GR g_rel round-trip.
// logit = S*(P*(2*alpha*g_abs + beta*g_rel)+gamma) written (pure store) to G.
// ===========================================================================
__global__ void __launch_bounds__(512) k_sp(
    const float* __restrict__ Q, const float* __restrict__ K, const float* __restrict__ x,
    const float* __restrict__ t, const float* __restrict__ gabs,
    const float4* __restrict__ TAB, const float4* __restrict__ NLIST,
    const int* __restrict__ NCNT,
    const float* __restrict__ alpha, const float* __restrict__ beta, const float* __restrict__ gamma,
    float* __restrict__ G)
{
    constexpr int PITCH = 68;
    int it = blockIdx.x, jt = blockIdx.y, bh = blockIdx.z;
    int b = bh >> 3, h = bh & 7;
    int i0 = it * 64, j0 = jt * 64;
    int tid = threadIdx.x;
    __shared__ __align__(16) float sm[4 * 32 * PITCH];   // 34816 B; tab reuses it
    float* sQ  = sm;
    float* sK  = sm + 32 * PITCH;
    float* sXi = sm + 64 * PITCH;
    float* sXj = sm + 96 * PITCH;

    {   // 512 threads: each stages one float4 per array (64 rows x 32 cols)
        int r = tid >> 3;
        int c4 = (tid & 7) * 4;
        float4 qv = *(const float4*)(Q + ((size_t)(b * Lc + i0 + r) * DMc + h * DHc + c4));
        float4 kv = *(const float4*)(K + ((size_t)(b * Lc + j0 + r) * DMc + h * DHc + c4));
        float4 xi = *(const float4*)(x + ((size_t)(b * Lc + i0 + r) * DMc + h * DHc + c4));
        float4 xj = *(const float4*)(x + ((size_t)(b * Lc + j0 + r) * DMc + h * DHc + c4));
        const float* q_ = (const float*)&qv; const float* k_ = (const float*)&kv;
        const float* a_ = (const float*)&xi; const float* c_ = (const float*)&xj;
        #pragma unroll
        for (int u = 0; u < 4; ++u) {
            sQ [(c4 + u) * PITCH + r] = q_[u];
            sK [(c4 + u) * PITCH + r] = k_[u];
            sXi[(c4 + u) * PITCH + r] = a_[u];
            sXj[(c4 + u) * PITCH + r] = c_[u];
        }
    }
    __syncthreads();

    int tx = tid & 15, ty = tid >> 4;    // ty in [0,32)
    int i2 = ty * 2, j4 = tx * 4;
    float accS[2][4] = {}, accP[2][4] = {};
    #pragma unroll 4
    for (int k = 0; k < 32; ++k) {
        float2 qa = *(const float2*)(sQ  + k * PITCH + i2);
        float4 kb = *(const float4*)(sK  + k * PITCH + j4);
        float2 xa = *(const float2*)(sXi + k * PITCH + i2);
        float4 xb = *(const float4*)(sXj + k * PITCH + j4);
        const float* qa_ = (const float*)&qa; const float* kb_ = (const float*)&kb;
        const float* xa_ = (const float*)&xa; const float* xb_ = (const float*)&xb;
        #pragma unroll
        for (int u = 0; u < 2; ++u)
            #pragma unroll
            for (int v = 0; v < 4; ++v) {
                accS[u][v] = fmaf(qa_[u], kb_[v], accS[u][v]);
                accP[u][v] = fmaf(xa_[u], xb_[v], accP[u][v]);
            }
    }

    // ---- stage per-head table into the (now dead) tile LDS ----
    __syncthreads();
    float4* tab = (float4*)sm;           // 4*NTAB float4 = 32 KB <= 34816 B
    {
        const float4* src = TAB + (size_t)h * 4 * NTAB;
        #pragma unroll
        for (int u = 0; u < 4; ++u)
            tab[tid + u * 512] = src[tid + u * 512];
    }
    __syncthreads();

    // ---- g_rel for this thread's 2x4 output points ----
    float4 tiv[2], tjv[4];
    #pragma unroll
    for (int u = 0; u < 2; ++u)
        tiv[u] = *(const float4*)(t + (size_t)(b * Lc + i0 + i2 + u) * 4);
    #pragma unroll
    for (int v = 0; v < 4; ++v)
        tjv[v] = *(const float4*)(t + (size_t)(b * Lc + j0 + j4 + v) * 4);

    float g8[2][4] = {};
    #pragma unroll
    for (int tg = 0; tg < 4; ++tg) {
        float xv[2][4];
        #pragma unroll
        for (int u = 0; u < 2; ++u) {
            float tiu = ((const float*)&tiv[u])[tg];
            #pragma unroll
            for (int v = 0; v < 4; ++v) {
                float xx = fabsf(tiu - ((const float*)&tjv[v])[tg]);
                xv[u][v] = xx;
                float xs = xx * (float)NTAB;
                int iu = min((int)xs, NTAB - 1);
                float uu = xs - (float)iu;
                float4 c = tab[tg * NTAB + iu];             // per-lane LDS gather
                g8[u][v] += fmaf(uu, fmaf(uu, c.z, c.y), c.x);
            }
        }
        int cn = NCNT[h * 4 + tg];                          // block-uniform
        for (int nn = 0; nn < cn; ++nn) {
            float4 q = NLIST[(h * 4 + tg) * 128 + nn];      // uniform s_load, hoisted over 8 pts
            #pragma unroll
            for (int u = 0; u < 2; ++u)
                #pragma unroll
                for (int v = 0; v < 4; ++v) {
                    float d0 = xv[u][v] - q.x;
                    g8[u][v] = fmaf(q.z, EXP2(d0 * d0 * q.y), g8[u][v]);
                }
        }
    }

    float la = alpha[h], lb = beta[h], lg = gamma[h];
    constexpr float SC = 1.0f / 32.0f;
    float* gb = G + (size_t)bh * (Lc * Lc);
    #pragma unroll
    for (int u = 0; u < 2; ++u) {
        int i = i0 + i2 + u;
        float gi2 = 2.0f * la * gabs[bh * Lc + i];
        float* addr = gb + (size_t)i * Lc + j0 + j4;
        float4 o;
        o.x = accS[u][0] * fmaf(accP[u][0], fmaf(lb, g8[u][0] * SC, gi2), lg);
        o.y = accS[u][1] * fmaf(accP[u][1], fmaf(lb, g8[u][1] * SC, gi2), lg);
        o.z = accS[u][2] * fmaf(accP[u][2], fmaf(lb, g8[u][2] * SC, gi2), lg);
        o.w = accS[u][3] * fmaf(accP[u][3], fmaf(lb, g8[u][3] * SC, gi2), lg);
        *(float4*)addr = o;   // pure store (was read-modify-write)
    }
}

// ===========================================================================
// kC: softmax fused into PV. grid (16,16), block 512. [unchanged]
// ===========================================================================
__global__ void __launch_bounds__(512) k_pvsm(const float* __restrict__ P,
                                              const float* __restrict__ V,
                                              float* __restrict__ AO) {
    int it = blockIdx.x, bh = blockIdx.y;
    int b = bh >> 3, h = bh & 7;
    int i0 = it * 16;
    int tid = threadIdx.x;
    __shared__ float sP[16 * 260];
    __shared__ float sV[256 * 34];
    int i = tid >> 5, l = tid & 31;

    const float* row = P + (size_t)bh * (Lc * Lc) + (size_t)(i0 + i) * Lc + l * 8;
    float4 p0 = *(const float4*)(row);
    float4 p1 = *(const float4*)(row + 4);
    float m = fmaxf(fmaxf(fmaxf(p0.x, p0.y), fmaxf(p0.z, p0.w)),
                    fmaxf(fmaxf(p1.x, p1.y), fmaxf(p1.z, p1.w)));
    #pragma unroll
    for (int s = 1; s < 32; s <<= 1) m = fmaxf(m, __shfl_xor(m, s, 32));
    float4 e0, e1;
    e0.x = EXP2((p0.x - m) * LOG2E); e0.y = EXP2((p0.y - m) * LOG2E);
    e0.z = EXP2((p0.z - m) * LOG2E); e0.w = EXP2((p0.w - m) * LOG2E);
    e1.x = EXP2((p1.x - m) * LOG2E); e1.y = EXP2((p1.y - m) * LOG2E);
    e1.z = EXP2((p1.z - m) * LOG2E); e1.w = EXP2((p1.w - m) * LOG2E);
    float sum = ((e0.x + e0.y) + (e0.z + e0.w)) + ((e1.x + e1.y) + (e1.z + e1.w));
    #pragma unroll
    for (int s = 1; s < 32; s <<= 1) sum += __shfl_xor(sum, s, 32);
    float rs = 1.0f / sum;
    *(float4*)(sP + i * 260 + l * 8)     = e0;
    *(float4*)(sP + i * 260 + l * 8 + 4) = e1;

    {   // stage V: 512 threads x 4 rows x float4
        int jr = tid >> 3, c4 = (tid & 7) * 4;
        #pragma unroll
        for (int u = 0; u < 4; ++u) {
            int j = jr + u * 64;
            *(float4*)(sV + j * 34 + c4) =
                *(const float4*)(V + ((size_t)(b * Lc + j) * DMc + h * DHc + c4));
        }
    }
    __syncthreads();

    int d = l;                  // one output column per thread
    float o0 = 0.f;
    #pragma unroll 4
    for (int j4 = 0; j4 < 256; j4 += 4) {
        float4 p4 = *(const float4*)(sP + i * 260 + j4);
        float v0 = sV[(j4 + 0) * 34 + d];
        float v1 = sV[(j4 + 1) * 34 + d];
        float v2 = sV[(j4 + 2) * 34 + d];
        float v3 = sV[(j4 + 3) * 34 + d];
        o0 = fmaf(p4.x, v0, o0); o0 = fmaf(p4.y, v1, o0);
        o0 = fmaf(p4.z, v2, o0); o0 = fmaf(p4.w, v3, o0);
    }
    AO[((size_t)(b * Lc + i0 + i) * DMc + h * DHc + d)] = o0 * rs;
}

// ===========================================================================
// kD: out = AO @ WO^T + bO.  grid (16,8), 32x32 tiles. [unchanged]
// ===========================================================================
__global__ void __launch_bounds__(256) k_out(const float* __restrict__ A,
                                             const float* __restrict__ W,
                                             const float* __restrict__ bias,
                                             float* __restrict__ C) {
    __shared__ float smem[2 * 16 * 33];
    gemm32(A, W, C, bias, 1.0f, blockIdx.x * 32, blockIdx.y * 32, smem);
}

// ===========================================================================
extern "C" void kernel_launch(void* const* d_in, const int* in_sizes, int n_in,
                              void* d_out, int out_size, void* d_ws, size_t ws_size,
                              hipStream_t stream) {
    (void)in_sizes; (void)n_in; (void)out_size; (void)ws_size;
    const float* x      = (const float*)d_in[0];
    const float* t      = (const float*)d_in[1];
    const float* WQ     = (const float*)d_in[2];
    const float* WK     = (const float*)d_in[3];
    const float* WV     = (const float*)d_in[4];
    const float* WO     = (const float*)d_in[5];
    const float* bO     = (const float*)d_in[6];
    const float* mu_abs = (const float*)d_in[7];
    const float* sg_abs = (const float*)d_in[8];
    const float* w_abs  = (const float*)d_in[9];
    const float* mu_rel = (const float*)d_in[10];
    const float* sg_rel = (const float*)d_in[11];
    const float* w_rel  = (const float*)d_in[12];
    const float* alpha  = (const float*)d_in[13];
    const float* beta   = (const float*)d_in[14];
    const float* gamma  = (const float*)d_in[15];
    float* out = (float*)d_out;
    float* ws = (float*)d_ws;

    float* Qb = ws;                // 131072 floats
    float* Kb = ws + 131072;
    float* Vb = ws + 262144;
    float* AO = ws + 393216;
    float* GA = ws + 524288;       // 4096
    float* GR = ws + 528384;       // 1048576 (logits)
    float4* TAB   = (float4*)(ws + 1576960);   // 32 x 512 x float4
    float4* NLIST = (float4*)(ws + 1642496);   // 32 x 128 x float4
    int*    NCNT  = (int*)   (ws + 1658880);   // 32 ints

    k_pre<<<dim3(576), dim3(256), 0, stream>>>(x, t, WQ, WK, WV,
                                               mu_abs, sg_abs, w_abs,
                                               mu_rel, sg_rel, w_rel,
                                               Qb, Kb, Vb, GA, TAB, NLIST, NCNT);
    k_sp<<<dim3(4, 4, 16), dim3(512), 0, stream>>>(Qb, Kb, x, t, GA,
                                                   TAB, NLIST, NCNT,
                                                   alpha, beta, gamma, GR);
    k_pvsm<<<dim3(16, 16), dim3(512), 0, stream>>>(GR, Vb, AO);
    k_out<<<dim3(16, 8), dim3(256), 0, stream>>>(AO, WO, bO, out);
}